// Round 1
// 539.663 us; speedup vs baseline: 1.0467x; 1.0467x over previous
//
#include <hip/hip_runtime.h>
#include <cstdint>
#include <cstddef>

#define NFEAT 128
#define KBUCK 1024

typedef __attribute__((ext_vector_type(8))) short bf16x8;
typedef __attribute__((ext_vector_type(4))) float f32x4;

// bf16 <-> f32 helpers (RNE, no NaN handling needed — activations are finite)
__device__ __forceinline__ unsigned short f2bf(float x) {
    union { float f; unsigned u; } v; v.f = x;
    unsigned r = v.u + 0x7fffu + ((v.u >> 16) & 1u);
    return (unsigned short)(r >> 16);
}
__device__ __forceinline__ float bf2f(unsigned short b) {
    union { unsigned u; float f; } v; v.u = ((unsigned)b) << 16;
    return v.f;
}

// ---------------- preprocessing kernels ----------------

__global__ void zero_ints(int* __restrict__ p, int n) {
    int i = blockIdx.x * blockDim.x + threadIdx.x;
    if (i < n) p[i] = 0;
}

__global__ void cast_bf16_kernel(const float* __restrict__ x, unsigned short* __restrict__ y, int n4) {
    int i = blockIdx.x * blockDim.x + threadIdx.x;
    if (i < n4) {
        float4 v = ((const float4*)x)[i];
        ushort4 o;
        o.x = f2bf(v.x); o.y = f2bf(v.y); o.z = f2bf(v.z); o.w = f2bf(v.w);
        ((ushort4*)y)[i] = o;
    }
}

// Pack Wcat (256 x NCOL: rows 0..127 = gcW, 128..255 = resW; fp32) into bf16 MFMA
// B-fragment order for K=256 GEMM:
// Wf[((kb*NT + nt)*64 + lane)*8 + j] = Wcat[kb*32 + (lane>>4)*8 + j][nt*16 + (lane&15)]
template <int NCOL>
__global__ void prep_wf2(const float* __restrict__ gcW, const float* __restrict__ resW,
                         unsigned short* __restrict__ Wf) {
    constexpr int NT = NCOL / 16;
    int tid = blockIdx.x * 256 + threadIdx.x;
    if (tid >= 256 * NCOL) return;
    int k = tid / NCOL, c = tid % NCOL;
    float v = (k < 128) ? gcW[k * NCOL + c] : resW[(k - 128) * NCOL + c];
    int kb = k >> 5, koff = k & 31, quad = koff >> 3, j = koff & 7;
    int nt = c >> 4, ncol = c & 15, lane = quad * 16 + ncol;
    Wf[((kb * NT + nt) * 64 + lane) * 8 + j] = f2bf(v);
}

// ---------------- fully-bucketed graph preprocessing (rounds 6-7) ----------------
// No global atomics to random addresses anywhere: bucket by node-range, per-bucket
// blocks count/scan/build in LDS with slice-local coalesced writes.

__global__ __launch_bounds__(256) void hist_kernel(
    const int* __restrict__ src, const int* __restrict__ dst, int ne, int D,
    int* __restrict__ dst_btot, int* __restrict__ src_btot) {
    __shared__ int hd[KBUCK], hs[KBUCK];
    const int t = threadIdx.x;
    const int tile0 = blockIdx.x * 4096;
    for (int i = t; i < KBUCK; i += 256) { hd[i] = 0; hs[i] = 0; }
    __syncthreads();
    #pragma unroll
    for (int j = 0; j < 16; j++) {
        int e = tile0 + j * 256 + t;
        if (e < ne) {
            atomicAdd(&hd[(unsigned)dst[e] / (unsigned)D], 1);
            atomicAdd(&hs[(unsigned)src[e] / (unsigned)D], 1);
        }
    }
    __syncthreads();
    for (int i = t; i < KBUCK; i += 256) {
        if (hd[i]) atomicAdd(&dst_btot[i], hd[i]);
        if (hs[i]) atomicAdd(&src_btot[i], hs[i]);
    }
}

__global__ __launch_bounds__(KBUCK) void scan_buckets(
    const int* __restrict__ dst_btot, const int* __restrict__ src_btot,
    int* __restrict__ dst_base, int* __restrict__ src_base,
    int* __restrict__ dst_cursor, int* __restrict__ src_cursor,
    int* __restrict__ row_ptr, int n, int ne) {
    __shared__ int t1[KBUCK], t2[KBUCK];
    const int t = threadIdx.x;
    int v1 = dst_btot[t], v2 = src_btot[t];
    t1[t] = v1; t2[t] = v2;
    for (int off = 1; off < KBUCK; off <<= 1) {
        __syncthreads();
        int a = (t >= off) ? t1[t - off] : 0;
        int b = (t >= off) ? t2[t - off] : 0;
        __syncthreads();
        t1[t] += a; t2[t] += b;
    }
    __syncthreads();
    int e1 = t1[t] - v1, e2 = t2[t] - v2;
    dst_base[t] = e1; src_base[t] = e2;
    dst_cursor[t] = e1; src_cursor[t] = e2;
    if (t == KBUCK - 1) {
        dst_base[KBUCK] = t1[t];
        src_base[KBUCK] = t2[t];
        row_ptr[n] = ne;
    }
}

__global__ __launch_bounds__(256) void partition_dst(
    const int* __restrict__ src, const int* __restrict__ dst, int ne, int D,
    int* __restrict__ dst_cursor, uint2* __restrict__ ebuf) {
    __shared__ int hist[KBUCK];
    __shared__ int gbase[KBUCK];
    const int t = threadIdx.x;
    const int tile0 = blockIdx.x * 4096;

    for (int i = t; i < KBUCK; i += 256) hist[i] = 0;
    __syncthreads();

    int s[16], d[16], r[16];
    #pragma unroll
    for (int j = 0; j < 16; j++) {
        int e = tile0 + j * 256 + t;
        if (e < ne) {
            s[j] = src[e];
            d[j] = dst[e];
            int b = (int)((unsigned)d[j] / (unsigned)D);
            r[j] = atomicAdd(&hist[b], 1);
        }
    }
    __syncthreads();
    for (int i = t; i < KBUCK; i += 256) {
        int c = hist[i];
        gbase[i] = c ? atomicAdd(&dst_cursor[i], c) : 0;
    }
    __syncthreads();
    #pragma unroll
    for (int j = 0; j < 16; j++) {
        int e = tile0 + j * 256 + t;
        if (e < ne) {
            int b = (int)((unsigned)d[j] / (unsigned)D);
            ebuf[gbase[b] + r[j]] = make_uint2((unsigned)s[j], (unsigned)d[j]);
        }
    }
}

__global__ __launch_bounds__(256) void partition_src(
    const int* __restrict__ src, int ne, int D,
    int* __restrict__ src_cursor, unsigned* __restrict__ sbuf) {
    __shared__ int hist[KBUCK];
    __shared__ int gbase[KBUCK];
    const int t = threadIdx.x;
    const int tile0 = blockIdx.x * 4096;

    for (int i = t; i < KBUCK; i += 256) hist[i] = 0;
    __syncthreads();

    int s[16], r[16];
    #pragma unroll
    for (int j = 0; j < 16; j++) {
        int e = tile0 + j * 256 + t;
        if (e < ne) {
            s[j] = src[e];
            int b = (int)((unsigned)s[j] / (unsigned)D);
            r[j] = atomicAdd(&hist[b], 1);
        }
    }
    __syncthreads();
    for (int i = t; i < KBUCK; i += 256) {
        int c = hist[i];
        gbase[i] = c ? atomicAdd(&src_cursor[i], c) : 0;
    }
    __syncthreads();
    #pragma unroll
    for (int j = 0; j < 16; j++) {
        int e = tile0 + j * 256 + t;
        if (e < ne) {
            int b = (int)((unsigned)s[j] / (unsigned)D);
            sbuf[gbase[b] + r[j]] = (unsigned)s[j];
        }
    }
}

// build_dst now emits fused CSR entries {src, norm_s[src]} (uint2) so the spmm
// gather has ONE level of random indirection instead of two. norm_s must be
// built first (build_src launched before build_dst).
__global__ __launch_bounds__(256) void build_dst(
    const uint2* __restrict__ ebuf, const int* __restrict__ dst_base,
    const float* __restrict__ norm_s,
    int n, int D, int* __restrict__ row_ptr, float* __restrict__ norm_d,
    uint2* __restrict__ csr_e) {
    __shared__ int cnt[128], sc[128], rp[128], rank[128];
    const int b = blockIdx.x;
    const int d_lo = b * D;
    if (d_lo >= n) return;
    const int d_hi = (d_lo + D < n) ? d_lo + D : n;
    const int e0 = dst_base[b], e1 = dst_base[b + 1];
    const int t = threadIdx.x;

    if (t < 128) { cnt[t] = 0; rank[t] = 0; }
    __syncthreads();
    for (int i = e0 + t; i < e1; i += 256)
        atomicAdd(&cnt[(int)ebuf[i].y - d_lo], 1);
    __syncthreads();
    if (t < 128) sc[t] = cnt[t];
    __syncthreads();
    for (int off = 1; off < 128; off <<= 1) {
        int v = (t < 128 && t >= off) ? sc[t - off] : 0;
        __syncthreads();
        if (t < 128) sc[t] += v;
        __syncthreads();
    }
    if (t < 128) {
        rp[t] = e0 + sc[t] - cnt[t];   // exclusive
        int d = d_lo + t;
        if (d < d_hi) {
            row_ptr[d] = rp[t];
            norm_d[d] = rsqrtf(fmaxf((float)cnt[t], 1.0f));
        }
    }
    __syncthreads();
    for (int i = e0 + t; i < e1; i += 256) {
        uint2 ed = ebuf[i];
        int dd = (int)ed.y - d_lo;
        int r = atomicAdd(&rank[dd], 1);
        csr_e[rp[dd] + r] = make_uint2(ed.x, __float_as_uint(norm_s[(int)ed.x]));
    }
}

__global__ __launch_bounds__(256) void build_src(
    const unsigned* __restrict__ sbuf, const int* __restrict__ src_base,
    int n, int D, float* __restrict__ norm_s) {
    __shared__ int cnt[128];
    const int b = blockIdx.x;
    const int d_lo = b * D;
    if (d_lo >= n) return;
    const int d_hi = (d_lo + D < n) ? d_lo + D : n;
    const int e0 = src_base[b], e1 = src_base[b + 1];
    const int t = threadIdx.x;
    if (t < 128) cnt[t] = 0;
    __syncthreads();
    for (int i = e0 + t; i < e1; i += 256)
        atomicAdd(&cnt[(int)sbuf[i] - d_lo], 1);
    __syncthreads();
    if (t < 128 && d_lo + t < d_hi)
        norm_s[d_lo + t] = rsqrtf(fmaxf((float)cnt[t], 1.0f));
}

// ---------------- aggregate-first SpMM: U = [norm_d .* (A@(norm_s.*x)) | A@x] ----------------
// Round-9: latency-bound fix. (a) CSR entries carry {src, norm_s[src]} — the
// per-edge random norm_s gather is gone; entry loads are streaming broadcasts.
// (b) 16-wide padded chunks: pad lanes clamp the index to the last valid edge
// (same address -> L1 hit, ~zero extra HBM traffic) so there is no serial tail
// and 16 row loads (4 KB) are in flight per wave.
// (c) readfirstlane-scalarized edge range / src indices / weights: row loads use
// scalar base addressing (saddr), weights live in SGPRs, VGPR stays low for
// full occupancy. Validity masks are wave-uniform scalar selects.

__global__ __launch_bounds__(256) void spmm_pre(
    const unsigned short* __restrict__ X, const int* __restrict__ row_ptr,
    const uint2* __restrict__ csr_e, const float* __restrict__ norm_d,
    unsigned short* __restrict__ U, int n) {
    int wid = (blockIdx.x * 256 + threadIdx.x) >> 6;
    int lane = threadIdx.x & 63;
    if (wid >= n) return;

    float ap0 = 0.f, ap1 = 0.f, as0 = 0.f, as1 = 0.f;
    const int e0 = __builtin_amdgcn_readfirstlane(row_ptr[wid]);
    const int e1 = __builtin_amdgcn_readfirstlane(row_ptr[wid + 1]);
    const unsigned short* Xl = X + lane * 2;

    for (int e = e0; e < e1; e += 16) {
        int s[16]; float wv[16];
        #pragma unroll
        for (int i = 0; i < 16; i++) {
            int idx = e + i;
            idx = (idx < e1) ? idx : (e1 - 1);
            uint2 E = csr_e[idx];
            s[i] = __builtin_amdgcn_readfirstlane((int)E.x);
            wv[i] = __uint_as_float(__builtin_amdgcn_readfirstlane((int)E.y));
        }
        ushort2 q[16];
        #pragma unroll
        for (int i = 0; i < 16; i++)
            q[i] = *(const ushort2*)(Xl + (size_t)s[i] * NFEAT);
        #pragma unroll
        for (int i = 0; i < 16; i++) {
            bool val = (e + i) < e1;          // wave-uniform scalar
            float wi = val ? wv[i] : 0.f;
            float mi = val ? 1.f : 0.f;
            float x0 = bf2f(q[i].x), x1 = bf2f(q[i].y);
            ap0 = fmaf(mi, x0, ap0); ap1 = fmaf(mi, x1, ap1);
            as0 = fmaf(wi, x0, as0); as1 = fmaf(wi, x1, as1);
        }
    }

    float nd = norm_d[wid];
    ushort2 gc, rs;
    gc.x = f2bf(nd * as0); gc.y = f2bf(nd * as1);
    rs.x = f2bf(ap0);      rs.y = f2bf(ap1);
    unsigned short* Ur = U + (size_t)wid * 256;
    *(ushort2*)(Ur + lane * 2) = gc;
    *(ushort2*)(Ur + 128 + lane * 2) = rs;
}

// ---------------- MFMA GEMM: y = U @ [W;R] + b (+relu), K=256 ----------------
// U: [M,256] bf16. Wf: fragment-major bf16 (prep_wf2). Block = 4 waves; wave w does
// rows blockIdx.x*64 + w*16, all NCOL cols. A (16x256) = 8 bf16x8 frags in registers.
// mfma_f32_16x16x32_bf16 layouts (HW-verified m89/m91): A[m=lane&15][k=(lane>>4)*8+j],
// C/D col=lane&15, row=(lane>>4)*4+reg.

template <int NCOL, bool RELU, bool OUT_BF16>
__global__ __launch_bounds__(256) void gemm_mfma(
    const unsigned short* __restrict__ U, int M,
    const unsigned short* __restrict__ Wf,
    const float* __restrict__ bias, void* __restrict__ outv) {
    constexpr int NT = NCOL / 16;
    __shared__ unsigned short Bs[256 * NCOL];

    const int t = threadIdx.x;
    const int wave = t >> 6, lane = t & 63;
    const int r0 = blockIdx.x * 64 + wave * 16;

    // stage Wf -> LDS (contiguous 16B copies, conflict-free)
    constexpr int TOT16 = 256 * NCOL * 2 / 16;
    const uint4* gsrc = (const uint4*)Wf;
    uint4* ldst = (uint4*)Bs;
    for (int i = t; i < TOT16; i += 256) ldst[i] = gsrc[i];

    // A fragments (rows am = r0 + (lane&15), k = kb*32 + (lane>>4)*8 + j)
    const int am = r0 + (lane & 15);
    const int kq = (lane >> 4) * 8;
    bf16x8 afrag[8];
    if (am < M) {
        const unsigned short* ap = U + (size_t)am * 256 + kq;
        #pragma unroll
        for (int kb = 0; kb < 8; kb++)
            afrag[kb] = *(const bf16x8*)(ap + kb * 32);
    } else {
        #pragma unroll
        for (int kb = 0; kb < 8; kb++) afrag[kb] = bf16x8{};
    }

    const int orow = r0 + (lane >> 4) * 4;
    __syncthreads();

    #pragma unroll 1
    for (int nt = 0; nt < NT; nt++) {
        f32x4 acc = {0.f, 0.f, 0.f, 0.f};
        #pragma unroll
        for (int kb = 0; kb < 8; kb++) {
            bf16x8 b = *(const bf16x8*)(Bs + ((kb * NT + nt) * 64 + lane) * 8);
            acc = __builtin_amdgcn_mfma_f32_16x16x32_bf16(afrag[kb], b, acc, 0, 0, 0);
        }
        const int gcol = nt * 16 + (lane & 15);
        const float bv = bias[gcol];
        #pragma unroll
        for (int r = 0; r < 4; r++) {
            int gm = orow + r;
            if (gm < M) {
                float v = acc[r] + bv;
                if (RELU) v = fmaxf(v, 0.f);
                if constexpr (OUT_BF16)
                    ((unsigned short*)outv)[(size_t)gm * NCOL + gcol] = f2bf(v);
                else
                    ((float*)outv)[(size_t)gm * NCOL + gcol] = v;
            }
        }
    }
}

// ---------------- launch ----------------

extern "C" void kernel_launch(void* const* d_in, const int* in_sizes, int n_in,
                              void* d_out, int out_size, void* d_ws, size_t ws_size,
                              hipStream_t stream) {
    const float* raw_x  = (const float*)d_in[0];
    const int*   src    = (const int*)d_in[1];
    const int*   dst    = (const int*)d_in[2];
    const float* gc_w0  = (const float*)d_in[3];
    const float* gc_b0  = (const float*)d_in[4];
    const float* gc_w1  = (const float*)d_in[5];
    const float* gc_b1  = (const float*)d_in[6];
    const float* gc_w2  = (const float*)d_in[7];
    const float* gc_b2  = (const float*)d_in[8];
    const float* res_w0 = (const float*)d_in[9];
    const float* res_w1 = (const float*)d_in[10];
    const float* res_w2 = (const float*)d_in[11];

    const int n  = in_sizes[0] / NFEAT;   // 100000
    const int ne = in_sizes[1];           // 1600000
    float* out = (float*)d_out;
    const int D = (n + KBUCK - 1) / KBUCK;   // nodes per bucket (98, <=128)

    // workspace layout
    char* w = (char*)d_ws;
    unsigned short* U   = (unsigned short*)w; w += (size_t)n * 256 * sizeof(unsigned short); // 51.2 MB
    unsigned short* Xb  = (unsigned short*)w; w += (size_t)n * 128 * sizeof(unsigned short); // 25.6 MB
    unsigned short* X1b = (unsigned short*)w; w += (size_t)n * 128 * sizeof(unsigned short); // 25.6 MB
    float* norm_s = (float*)w;   w += (size_t)n * sizeof(float);
    float* norm_d = (float*)w;   w += (size_t)n * sizeof(float);
    int* row_ptr = (int*)w;      w += (size_t)(n + 1) * sizeof(int);
    uint2* csr_e = (uint2*)w;    w += (size_t)ne * sizeof(uint2);      // 12.8 MB {src, ns}
    uint2* ebuf = (uint2*)w;     w += (size_t)ne * sizeof(uint2);      // 12.8 MB
    unsigned* sbuf = (unsigned*)w; w += (size_t)ne * sizeof(unsigned); // 6.4 MB
    int* dst_btot = (int*)w;     w += KBUCK * sizeof(int);
    int* src_btot = (int*)w;     w += KBUCK * sizeof(int);
    int* dst_base = (int*)w;     w += (KBUCK + 1) * sizeof(int);
    int* src_base = (int*)w;     w += (KBUCK + 1) * sizeof(int);
    int* dst_cursor = (int*)w;   w += KBUCK * sizeof(int);
    int* src_cursor = (int*)w;   w += KBUCK * sizeof(int);
    unsigned short* Wf0 = (unsigned short*)w; w += 256 * 128 * sizeof(unsigned short);
    unsigned short* Wf1 = (unsigned short*)w; w += 256 * 128 * sizeof(unsigned short);
    unsigned short* Wf2 = (unsigned short*)w; w += 256 * 64 * sizeof(unsigned short);

    const int tiles = (ne + 4095) / 4096;

    // --- preprocessing: bf16 cast, weight fragments, bucketed CSR + degrees ---
    cast_bf16_kernel<<<(n * (NFEAT / 4) + 255) / 256, 256, 0, stream>>>(raw_x, Xb, n * (NFEAT / 4));
    prep_wf2<128><<<128, 256, 0, stream>>>(gc_w0, res_w0, Wf0);
    prep_wf2<128><<<128, 256, 0, stream>>>(gc_w1, res_w1, Wf1);
    prep_wf2<64><<<64, 256, 0, stream>>>(gc_w2, res_w2, Wf2);
    zero_ints<<<(2 * KBUCK + 255) / 256, 256, 0, stream>>>(dst_btot, 2 * KBUCK); // dst_btot+src_btot contiguous
    hist_kernel<<<tiles, 256, 0, stream>>>(src, dst, ne, D, dst_btot, src_btot);
    scan_buckets<<<1, KBUCK, 0, stream>>>(dst_btot, src_btot, dst_base, src_base,
                                          dst_cursor, src_cursor, row_ptr, n, ne);
    partition_dst<<<tiles, 256, 0, stream>>>(src, dst, ne, D, dst_cursor, ebuf);
    partition_src<<<tiles, 256, 0, stream>>>(src, ne, D, src_cursor, sbuf);
    build_src<<<KBUCK, 256, 0, stream>>>(sbuf, src_base, n, D, norm_s);
    build_dst<<<KBUCK, 256, 0, stream>>>(ebuf, dst_base, norm_s, n, D, row_ptr, norm_d, csr_e);

    const int gemm_blocks = (n + 63) / 64;
    const int spmm_blocks = (n + 3) / 4;

    // --- layer 0: x1 = relu([nd*A(ns*x) | A x] @ [W0;R0] + b0) ---
    spmm_pre<<<spmm_blocks, 256, 0, stream>>>(Xb, row_ptr, csr_e, norm_d, U, n);
    gemm_mfma<128, true, true><<<gemm_blocks, 256, 0, stream>>>(U, n, Wf0, gc_b0, X1b);

    // --- layer 1 ---
    spmm_pre<<<spmm_blocks, 256, 0, stream>>>(X1b, row_ptr, csr_e, norm_d, U, n);
    gemm_mfma<128, true, true><<<gemm_blocks, 256, 0, stream>>>(U, n, Wf1, gc_b1, X1b);

    // --- layer 2: output 64-wide fp32, no relu ---
    spmm_pre<<<spmm_blocks, 256, 0, stream>>>(X1b, row_ptr, csr_e, norm_d, U, n);
    gemm_mfma<64, false, false><<<gemm_blocks, 256, 0, stream>>>(U, n, Wf2, gc_b2, out);
}